// Round 6
// baseline (3130.858 us; speedup 1.0000x reference)
//
#include <hip/hip_runtime.h>

#define NN 100000
#define D 128
#define D2 256

typedef unsigned short u16;
typedef unsigned int u32;

__device__ __forceinline__ u16 f2bf(float f) {
  union { float f; u32 u; } v; v.f = f;
  u32 r = v.u + 0x7fffu + ((v.u >> 16) & 1u);   // round-nearest-even
  return (u16)(r >> 16);
}
__device__ __forceinline__ float bf2f(u16 u) {
  union { u32 u; float f; } v; v.u = ((u32)u) << 16;
  return v.f;
}
__device__ __forceinline__ void fma4(float4& acc, float a, const float4& w) {
  acc.x = fmaf(a, w.x, acc.x);
  acc.y = fmaf(a, w.y, acc.y);
  acc.z = fmaf(a, w.z, acc.z);
  acc.w = fmaf(a, w.w, acc.w);
}

// K0: h0 = (1+eps)*x into d_out; zero BN stat accumulators (2 KB of ws)
__global__ void k_init(const float* __restrict__ x, const float* __restrict__ epsp,
                       float* __restrict__ h0, float* __restrict__ stats) {
  if (blockIdx.x == 0 && threadIdx.x < 512) stats[threadIdx.x] = 0.0f;
  const float ep = 1.0f + epsp[0];
  const float4* x4 = (const float4*)x;
  float4* h4 = (float4*)h0;
  const int total = NN * D / 4;
  for (int i = blockIdx.x * blockDim.x + threadIdx.x; i < total;
       i += gridDim.x * blockDim.x) {
    float4 v = x4[i];
    v.x *= ep; v.y *= ep; v.z *= ep; v.w *= ep;
    h4[i] = v;
  }
}

// K1: one wave per edge (8 edges/wave): h0[dst] += x[src] via f32 atomics.
// NOTE: harness delivers integer inputs as int32 (NOT the reference's int64).
__global__ void k_edges(const float* __restrict__ x, const int* __restrict__ srcs,
                        const int* __restrict__ dsts, float* __restrict__ h0,
                        int E) {
  const int lane = threadIdx.x & 63;
  const int wave = blockIdx.x * (blockDim.x >> 6) + (threadIdx.x >> 6);
  const int e0 = wave * 8;
  const int e1 = min(e0 + 8, E);
  for (int e = e0; e < e1; ++e) {
    const int s = srcs[e];
    const int d = dsts[e];
    const float2 v = ((const float2*)(x + (size_t)s * D))[lane];
    float* p = h0 + (size_t)d * D + lane * 2;
    unsafeAtomicAdd(p, v.x);
    unsafeAtomicAdd(p + 1, v.y);
  }
}

// K2: h1(bf16, IN PLACE over h0) = h0 @ W1 + b1 ; fused BN partial stats.
// h0 and h1 alias the same bytes of d_out (row r: 128 f32 <-> 256 bf16, both
// 512 B). Each row is read and written only by its owning wave; stores happen
// after all loads of that row. Pointers intentionally NOT __restrict__.
__global__ __launch_bounds__(1024) void k_gemm1(const float* h0, u16* h1,
    const float* __restrict__ W1, const float* __restrict__ b1,
    float* __restrict__ stats) {
  __shared__ float4 sW[D * D2 / 4];             // 128 KiB, W1 f32
  const float4* Wv = (const float4*)W1;
  for (int i = threadIdx.x; i < D * D2 / 4; i += 1024) sW[i] = Wv[i];
  __syncthreads();
  const int lane = threadIdx.x & 63;
  const int wv = blockIdx.x * 16 + (threadIdx.x >> 6);
  const int nwv = gridDim.x * 16;
  const float4 bias = ((const float4*)b1)[lane]; // cols lane*4..+3
  float ssum[4] = {0.f, 0.f, 0.f, 0.f};
  float sqs[4]  = {0.f, 0.f, 0.f, 0.f};
  for (int rb = wv * 8; rb < NN; rb += nwv * 8) {
    float4 acc[8];
    #pragma unroll
    for (int r = 0; r < 8; ++r) acc[r] = bias;
    for (int k4 = 0; k4 < D / 4; ++k4) {
      const float4 w0 = sW[(k4 * 4 + 0) * (D2 / 4) + lane];
      const float4 w1 = sW[(k4 * 4 + 1) * (D2 / 4) + lane];
      const float4 w2 = sW[(k4 * 4 + 2) * (D2 / 4) + lane];
      const float4 w3 = sW[(k4 * 4 + 3) * (D2 / 4) + lane];
      #pragma unroll
      for (int r = 0; r < 8; ++r) {
        const float4 a = ((const float4*)(h0 + (size_t)(rb + r) * D))[k4];
        fma4(acc[r], a.x, w0);
        fma4(acc[r], a.y, w1);
        fma4(acc[r], a.z, w2);
        fma4(acc[r], a.w, w3);
      }
    }
    #pragma unroll
    for (int r = 0; r < 8; ++r) {
      ushort4 o;
      o.x = f2bf(acc[r].x); o.y = f2bf(acc[r].y);
      o.z = f2bf(acc[r].z); o.w = f2bf(acc[r].w);
      ((ushort4*)h1)[(size_t)(rb + r) * (D2 / 4) + lane] = o;
      ssum[0] += acc[r].x; ssum[1] += acc[r].y;
      ssum[2] += acc[r].z; ssum[3] += acc[r].w;
      sqs[0] += acc[r].x * acc[r].x; sqs[1] += acc[r].y * acc[r].y;
      sqs[2] += acc[r].z * acc[r].z; sqs[3] += acc[r].w * acc[r].w;
    }
  }
  // block reduction: per-wave partial rows in LDS, strided tree, 1 atomic/slot
  __syncthreads();
  float* red = (float*)sW;                      // reuse LDS: [16][512]
  const int w = threadIdx.x >> 6;
  #pragma unroll
  for (int c = 0; c < 4; ++c) {
    red[w * 512 + lane * 4 + c] = ssum[c];
    red[w * 512 + 256 + lane * 4 + c] = sqs[c];
  }
  __syncthreads();
  if (threadIdx.x < 512) {
    float s = 0.f;
    #pragma unroll
    for (int ww = 0; ww < 16; ++ww) s += red[ww * 512 + threadIdx.x];
    unsafeAtomicAdd(&stats[threadIdx.x], s);
  }
}

// K3: finalize BN scale/shift (1 block, 256 threads)
__global__ void k_finalize(const float* __restrict__ gamma, const float* __restrict__ beta,
                           float* __restrict__ stats) {
  const int j = threadIdx.x;
  const float inv = 1.0f / (float)NN;
  const float mu = stats[j] * inv;
  const float var = fmaxf(stats[D2 + j] * inv - mu * mu, 0.0f);
  const float sc = gamma[j] * rsqrtf(var + 1e-5f);
  stats[2 * D2 + j] = sc;
  stats[3 * D2 + j] = beta[j] - mu * sc;
}

// K4: out(f32, IN PLACE over h1) = relu(s*h1+t) @ W2 + b2. Same aliasing
// discipline as K2 (no __restrict__ on h1/outp).
__global__ __launch_bounds__(1024) void k_gemm2(const u16* h1, float* outp,
    const float* __restrict__ W2, const float* __restrict__ b2,
    const float* __restrict__ stats) {
  __shared__ float4 sW[D2 * D / 4];             // 128 KiB, W2 f32
  __shared__ float sS[D2], sT[D2];
  const float4* Wv = (const float4*)W2;
  for (int i = threadIdx.x; i < D2 * D / 4; i += 1024) sW[i] = Wv[i];
  if (threadIdx.x < D2) {
    sS[threadIdx.x] = stats[2 * D2 + threadIdx.x];
    sT[threadIdx.x] = stats[3 * D2 + threadIdx.x];
  }
  __syncthreads();
  const float2* sWf2 = (const float2*)sW;
  const int lane = threadIdx.x & 63;
  const int wv = blockIdx.x * 16 + (threadIdx.x >> 6);
  const int nwv = gridDim.x * 16;
  const float2 bias = ((const float2*)b2)[lane]; // cols lane*2..+1
  for (int rb = wv * 8; rb < NN; rb += nwv * 8) {
    float2 acc[8];
    #pragma unroll
    for (int r = 0; r < 8; ++r) acc[r] = bias;
    for (int k4 = 0; k4 < D2 / 4; ++k4) {
      const float4 sv = ((const float4*)sS)[k4];
      const float4 tv = ((const float4*)sT)[k4];
      const float2 w0 = sWf2[(k4 * 4 + 0) * 64 + lane];
      const float2 w1 = sWf2[(k4 * 4 + 1) * 64 + lane];
      const float2 w2 = sWf2[(k4 * 4 + 2) * 64 + lane];
      const float2 w3 = sWf2[(k4 * 4 + 3) * 64 + lane];
      #pragma unroll
      for (int r = 0; r < 8; ++r) {
        const ushort4 a = ((const ushort4*)h1)[(size_t)(rb + r) * 64 + k4];
        const float ha = fmaxf(fmaf(bf2f(a.x), sv.x, tv.x), 0.f);
        const float hb = fmaxf(fmaf(bf2f(a.y), sv.y, tv.y), 0.f);
        const float hc = fmaxf(fmaf(bf2f(a.z), sv.z, tv.z), 0.f);
        const float hd = fmaxf(fmaf(bf2f(a.w), sv.w, tv.w), 0.f);
        acc[r].x = fmaf(ha, w0.x, acc[r].x); acc[r].y = fmaf(ha, w0.y, acc[r].y);
        acc[r].x = fmaf(hb, w1.x, acc[r].x); acc[r].y = fmaf(hb, w1.y, acc[r].y);
        acc[r].x = fmaf(hc, w2.x, acc[r].x); acc[r].y = fmaf(hc, w2.y, acc[r].y);
        acc[r].x = fmaf(hd, w3.x, acc[r].x); acc[r].y = fmaf(hd, w3.y, acc[r].y);
      }
    }
    #pragma unroll
    for (int r = 0; r < 8; ++r)
      ((float2*)outp)[(size_t)(rb + r) * 64 + lane] = acc[r];
  }
}

extern "C" void kernel_launch(void* const* d_in, const int* in_sizes, int n_in,
                              void* d_out, int out_size, void* d_ws, size_t ws_size,
                              hipStream_t stream) {
  const float* x     = (const float*)d_in[0];
  const int* ei      = (const int*)d_in[1];     // int32! harness converts int64
  const float* W1    = (const float*)d_in[2];
  const float* b1    = (const float*)d_in[3];
  const float* gamma = (const float*)d_in[4];
  const float* beta  = (const float*)d_in[5];
  const float* W2    = (const float*)d_in[6];
  const float* b2    = (const float*)d_in[7];
  const float* eps   = (const float*)d_in[8];
  const int E = in_sizes[1] / 2;

  float* out   = (float*)d_out;     // 51.2 MB: h0 (f32) -> h1 (bf16) -> out (f32)
  float* stats = (float*)d_ws;      // 4 KB: sum[256] sumsq[256] s[256] t[256]

  k_init<<<2048, 256, 0, stream>>>(x, eps, out, stats);
  const int epb = 32;               // 4 waves/block * 8 edges/wave
  k_edges<<<(E + epb - 1) / epb, 256, 0, stream>>>(x, ei, ei + E, out, E);
  k_gemm1<<<256, 1024, 0, stream>>>(out, (u16*)out, W1, b1, stats);
  k_finalize<<<1, 256, 0, stream>>>(gamma, beta, stats);
  k_gemm2<<<256, 1024, 0, stream>>>((const u16*)out, out, W2, b2, stats);
}

// Round 8
// 1377.321 us; speedup vs baseline: 2.2732x; 2.2732x over previous
//
#include <hip/hip_runtime.h>

#define NN 100000
#define D 128
#define D2 256
#define SCAN_T 1024
#define SCAN_CH ((NN + SCAN_T - 1) / SCAN_T)   // 98

typedef unsigned short u16;
typedef unsigned int u32;

__device__ __forceinline__ u16 f2bf(float f) {
  union { float f; u32 u; } v; v.f = f;
  u32 r = v.u + 0x7fffu + ((v.u >> 16) & 1u);   // round-nearest-even
  return (u16)(r >> 16);
}
__device__ __forceinline__ float bf2f(u16 u) {
  union { u32 u; float f; } v; v.u = ((u32)u) << 16;
  return v.f;
}
__device__ __forceinline__ void fma4(float4& acc, float a, const float4& w) {
  acc.x = fmaf(a, w.x, acc.x);
  acc.y = fmaf(a, w.y, acc.y);
  acc.z = fmaf(a, w.z, acc.z);
  acc.w = fmaf(a, w.w, acc.w);
}

// ---------- CSR build ----------
// C1: degree count (int atomics on 400 KB, L2-resident)
__global__ void k_count(const int* __restrict__ dsts, int* __restrict__ cnt, int E) {
  for (int e = blockIdx.x * blockDim.x + threadIdx.x; e < E;
       e += gridDim.x * blockDim.x)
    atomicAdd(&cnt[dsts[e]], 1);
}

// C2: single-block exclusive scan over cnt -> row_ptr; cursor (aliases cnt)
// is set to the row start so the scatter can bump it.
__global__ __launch_bounds__(SCAN_T) void k_scan(int* __restrict__ cnt,
                                                 int* __restrict__ row_ptr) {
  __shared__ int part[SCAN_T];
  const int t = threadIdx.x;
  const int lo = t * SCAN_CH;
  const int hi = min(lo + SCAN_CH, NN);
  int s = 0;
  for (int i = lo; i < hi; ++i) s += cnt[i];
  part[t] = s;
  __syncthreads();
  for (int off = 1; off < SCAN_T; off <<= 1) {      // Hillis-Steele inclusive
    int v = (t >= off) ? part[t - off] : 0;
    __syncthreads();
    part[t] += v;
    __syncthreads();
  }
  int base = (t == 0) ? 0 : part[t - 1];
  for (int i = lo; i < hi; ++i) {
    const int c = cnt[i];          // read BEFORE clobbering (cursor aliases cnt)
    row_ptr[i] = base;
    cnt[i] = base;                 // cursor init = row start
    base += c;
  }
  if (t == SCAN_T - 1) row_ptr[NN] = part[SCAN_T - 1];
}

// C3: scatter src indices into CSR order
__global__ void k_scatter(const int* __restrict__ srcs, const int* __restrict__ dsts,
                          int* __restrict__ cursor, int* __restrict__ csr, int E) {
  for (int e = blockIdx.x * blockDim.x + threadIdx.x; e < E;
       e += gridDim.x * blockDim.x) {
    const int pos = atomicAdd(&cursor[dsts[e]], 1);
    csr[pos] = srcs[e];
  }
}

// C4: one wave per node: h0[v] = (1+eps)*x[v] + sum_{u in N(v)} x[u]
__global__ __launch_bounds__(256) void k_aggregate(const float* __restrict__ x,
    const float* __restrict__ epsp, const int* __restrict__ rowp,
    const int* __restrict__ csr, float* __restrict__ h0) {
  const int lane = threadIdx.x & 63;
  const int wid = blockIdx.x * 4 + (threadIdx.x >> 6);
  const int nw = gridDim.x * 4;
  const float ep = 1.0f + epsp[0];
  for (int v = wid; v < NN; v += nw) {
    const float2 xv = ((const float2*)(x + (size_t)v * D))[lane];
    float2 acc;
    acc.x = ep * xv.x;
    acc.y = ep * xv.y;
    const int beg = rowp[v], end = rowp[v + 1];
    int j = beg;
    for (; j + 4 <= end; j += 4) {          // 4 independent gathers in flight
      const int u0 = csr[j + 0], u1 = csr[j + 1];
      const int u2 = csr[j + 2], u3 = csr[j + 3];
      const float2 a0 = ((const float2*)(x + (size_t)u0 * D))[lane];
      const float2 a1 = ((const float2*)(x + (size_t)u1 * D))[lane];
      const float2 a2 = ((const float2*)(x + (size_t)u2 * D))[lane];
      const float2 a3 = ((const float2*)(x + (size_t)u3 * D))[lane];
      acc.x += a0.x + a1.x + a2.x + a3.x;
      acc.y += a0.y + a1.y + a2.y + a3.y;
    }
    for (; j < end; ++j) {
      const float2 a = ((const float2*)(x + (size_t)csr[j] * D))[lane];
      acc.x += a.x;
      acc.y += a.y;
    }
    ((float2*)(h0 + (size_t)v * D))[lane] = acc;
  }
}

// ---------- fallback (proven R6 path) ----------
__global__ void k_init(const float* __restrict__ x, const float* __restrict__ epsp,
                       float* __restrict__ h0, float* __restrict__ stats) {
  if (blockIdx.x == 0 && threadIdx.x < 512) stats[threadIdx.x] = 0.0f;
  const float ep = 1.0f + epsp[0];
  const float4* x4 = (const float4*)x;
  float4* h4 = (float4*)h0;
  const int total = NN * D / 4;
  for (int i = blockIdx.x * blockDim.x + threadIdx.x; i < total;
       i += gridDim.x * blockDim.x) {
    float4 v = x4[i];
    v.x *= ep; v.y *= ep; v.z *= ep; v.w *= ep;
    h4[i] = v;
  }
}

__global__ void k_edges(const float* __restrict__ x, const int* __restrict__ srcs,
                        const int* __restrict__ dsts, float* __restrict__ h0,
                        int E) {
  const int lane = threadIdx.x & 63;
  const int wave = blockIdx.x * (blockDim.x >> 6) + (threadIdx.x >> 6);
  const int e0 = wave * 8;
  const int e1 = min(e0 + 8, E);
  for (int e = e0; e < e1; ++e) {
    const int s = srcs[e];
    const int d = dsts[e];
    const float2 v = ((const float2*)(x + (size_t)s * D))[lane];
    float* p = h0 + (size_t)d * D + lane * 2;
    unsafeAtomicAdd(p, v.x);
    unsafeAtomicAdd(p + 1, v.y);
  }
}

// ---------- MLP (unchanged from R6) ----------
// K2: h1(bf16, IN PLACE over h0) = h0 @ W1 + b1 ; fused BN partial stats.
__global__ __launch_bounds__(1024) void k_gemm1(const float* h0, u16* h1,
    const float* __restrict__ W1, const float* __restrict__ b1,
    float* __restrict__ stats) {
  __shared__ float4 sW[D * D2 / 4];             // 128 KiB, W1 f32
  const float4* Wv = (const float4*)W1;
  for (int i = threadIdx.x; i < D * D2 / 4; i += 1024) sW[i] = Wv[i];
  __syncthreads();
  const int lane = threadIdx.x & 63;
  const int wv = blockIdx.x * 16 + (threadIdx.x >> 6);
  const int nwv = gridDim.x * 16;
  const float4 bias = ((const float4*)b1)[lane];
  float ssum[4] = {0.f, 0.f, 0.f, 0.f};
  float sqs[4]  = {0.f, 0.f, 0.f, 0.f};
  for (int rb = wv * 8; rb < NN; rb += nwv * 8) {
    float4 acc[8];
    #pragma unroll
    for (int r = 0; r < 8; ++r) acc[r] = bias;
    for (int k4 = 0; k4 < D / 4; ++k4) {
      const float4 w0 = sW[(k4 * 4 + 0) * (D2 / 4) + lane];
      const float4 w1 = sW[(k4 * 4 + 1) * (D2 / 4) + lane];
      const float4 w2 = sW[(k4 * 4 + 2) * (D2 / 4) + lane];
      const float4 w3 = sW[(k4 * 4 + 3) * (D2 / 4) + lane];
      #pragma unroll
      for (int r = 0; r < 8; ++r) {
        const float4 a = ((const float4*)(h0 + (size_t)(rb + r) * D))[k4];
        fma4(acc[r], a.x, w0);
        fma4(acc[r], a.y, w1);
        fma4(acc[r], a.z, w2);
        fma4(acc[r], a.w, w3);
      }
    }
    #pragma unroll
    for (int r = 0; r < 8; ++r) {
      ushort4 o;
      o.x = f2bf(acc[r].x); o.y = f2bf(acc[r].y);
      o.z = f2bf(acc[r].z); o.w = f2bf(acc[r].w);
      ((ushort4*)h1)[(size_t)(rb + r) * (D2 / 4) + lane] = o;
      ssum[0] += acc[r].x; ssum[1] += acc[r].y;
      ssum[2] += acc[r].z; ssum[3] += acc[r].w;
      sqs[0] += acc[r].x * acc[r].x; sqs[1] += acc[r].y * acc[r].y;
      sqs[2] += acc[r].z * acc[r].z; sqs[3] += acc[r].w * acc[r].w;
    }
  }
  __syncthreads();
  float* red = (float*)sW;                      // reuse LDS: [16][512]
  const int w = threadIdx.x >> 6;
  #pragma unroll
  for (int c = 0; c < 4; ++c) {
    red[w * 512 + lane * 4 + c] = ssum[c];
    red[w * 512 + 256 + lane * 4 + c] = sqs[c];
  }
  __syncthreads();
  if (threadIdx.x < 512) {
    float s = 0.f;
    #pragma unroll
    for (int ww = 0; ww < 16; ++ww) s += red[ww * 512 + threadIdx.x];
    unsafeAtomicAdd(&stats[threadIdx.x], s);
  }
}

__global__ void k_finalize(const float* __restrict__ gamma, const float* __restrict__ beta,
                           float* __restrict__ stats) {
  const int j = threadIdx.x;
  const float inv = 1.0f / (float)NN;
  const float mu = stats[j] * inv;
  const float var = fmaxf(stats[D2 + j] * inv - mu * mu, 0.0f);
  const float sc = gamma[j] * rsqrtf(var + 1e-5f);
  stats[2 * D2 + j] = sc;
  stats[3 * D2 + j] = beta[j] - mu * sc;
}

// K4: out(f32, IN PLACE over h1) = relu(s*h1+t) @ W2 + b2.
__global__ __launch_bounds__(1024) void k_gemm2(const u16* h1, float* outp,
    const float* __restrict__ W2, const float* __restrict__ b2,
    const float* __restrict__ stats) {
  __shared__ float4 sW[D2 * D / 4];             // 128 KiB, W2 f32
  __shared__ float sS[D2], sT[D2];
  const float4* Wv = (const float4*)W2;
  for (int i = threadIdx.x; i < D2 * D / 4; i += 1024) sW[i] = Wv[i];
  if (threadIdx.x < D2) {
    sS[threadIdx.x] = stats[2 * D2 + threadIdx.x];
    sT[threadIdx.x] = stats[3 * D2 + threadIdx.x];
  }
  __syncthreads();
  const float2* sWf2 = (const float2*)sW;
  const int lane = threadIdx.x & 63;
  const int wv = blockIdx.x * 16 + (threadIdx.x >> 6);
  const int nwv = gridDim.x * 16;
  const float2 bias = ((const float2*)b2)[lane];
  for (int rb = wv * 8; rb < NN; rb += nwv * 8) {
    float2 acc[8];
    #pragma unroll
    for (int r = 0; r < 8; ++r) acc[r] = bias;
    for (int k4 = 0; k4 < D2 / 4; ++k4) {
      const float4 sv = ((const float4*)sS)[k4];
      const float4 tv = ((const float4*)sT)[k4];
      const float2 w0 = sWf2[(k4 * 4 + 0) * 64 + lane];
      const float2 w1 = sWf2[(k4 * 4 + 1) * 64 + lane];
      const float2 w2 = sWf2[(k4 * 4 + 2) * 64 + lane];
      const float2 w3 = sWf2[(k4 * 4 + 3) * 64 + lane];
      #pragma unroll
      for (int r = 0; r < 8; ++r) {
        const ushort4 a = ((const ushort4*)h1)[(size_t)(rb + r) * 64 + k4];
        const float ha = fmaxf(fmaf(bf2f(a.x), sv.x, tv.x), 0.f);
        const float hb = fmaxf(fmaf(bf2f(a.y), sv.y, tv.y), 0.f);
        const float hc = fmaxf(fmaf(bf2f(a.z), sv.z, tv.z), 0.f);
        const float hd = fmaxf(fmaf(bf2f(a.w), sv.w, tv.w), 0.f);
        acc[r].x = fmaf(ha, w0.x, acc[r].x); acc[r].y = fmaf(ha, w0.y, acc[r].y);
        acc[r].x = fmaf(hb, w1.x, acc[r].x); acc[r].y = fmaf(hb, w1.y, acc[r].y);
        acc[r].x = fmaf(hc, w2.x, acc[r].x); acc[r].y = fmaf(hc, w2.y, acc[r].y);
        acc[r].x = fmaf(hd, w3.x, acc[r].x); acc[r].y = fmaf(hd, w3.y, acc[r].y);
      }
    }
    #pragma unroll
    for (int r = 0; r < 8; ++r)
      ((float2*)outp)[(size_t)(rb + r) * 64 + lane] = acc[r];
  }
}

extern "C" void kernel_launch(void* const* d_in, const int* in_sizes, int n_in,
                              void* d_out, int out_size, void* d_ws, size_t ws_size,
                              hipStream_t stream) {
  const float* x     = (const float*)d_in[0];
  const int* ei      = (const int*)d_in[1];     // int32 (harness converts int64)
  const float* W1    = (const float*)d_in[2];
  const float* b1    = (const float*)d_in[3];
  const float* gamma = (const float*)d_in[4];
  const float* beta  = (const float*)d_in[5];
  const float* W2    = (const float*)d_in[6];
  const float* b2    = (const float*)d_in[7];
  const float* eps   = (const float*)d_in[8];
  const int E = in_sizes[1] / 2;

  float* out   = (float*)d_out;     // h0 (f32) -> h1 (bf16) -> out (f32), in place
  float* stats = (float*)d_ws;      // 4 KB
  int* cnt  = (int*)((char*)d_ws + 4096);       // NN ints (doubles as cursor)
  int* rowp = cnt + NN;                          // NN+1 ints
  int* csr  = rowp + NN + 1;                     // E ints
  const size_t need = 4096 + sizeof(int) * ((size_t)NN + (NN + 1) + E);

  if (ws_size >= need) {
    hipMemsetAsync(d_ws, 0, 4096 + (size_t)NN * 4, stream);  // stats + cnt
    k_count<<<(E + 255) / 256, 256, 0, stream>>>(ei + E, cnt, E);
    k_scan<<<1, SCAN_T, 0, stream>>>(cnt, rowp);
    k_scatter<<<(E + 255) / 256, 256, 0, stream>>>(ei, ei + E, cnt, csr, E);
    k_aggregate<<<1600, 256, 0, stream>>>(x, eps, rowp, csr, out);
  } else {
    k_init<<<2048, 256, 0, stream>>>(x, eps, out, stats);
    k_edges<<<(E + 31) / 32, 256, 0, stream>>>(x, ei, ei + E, out, E);
  }
  k_gemm1<<<256, 1024, 0, stream>>>(out, (u16*)out, W1, b1, stats);
  k_finalize<<<1, 256, 0, stream>>>(gamma, beta, stats);
  k_gemm2<<<256, 1024, 0, stream>>>((const u16*)out, out, W2, b2, stats);
}

// Round 10
// 1091.543 us; speedup vs baseline: 2.8683x; 1.2618x over previous
//
#include <hip/hip_runtime.h>

#define NN 100000
#define D 128
#define D2 256
#define SCAN_T 1024
#define SCAN_CH ((NN + SCAN_T - 1) / SCAN_T)   // 98

typedef unsigned short u16;
typedef unsigned int u32;
typedef __attribute__((ext_vector_type(8))) short short8v;
typedef __attribute__((ext_vector_type(8))) unsigned short ushort8v;
typedef __attribute__((ext_vector_type(16))) float f32x16;

__device__ __forceinline__ u16 f2bf(float f) {
  union { float f; u32 u; } v; v.f = f;
  u32 r = v.u + 0x7fffu + ((v.u >> 16) & 1u);   // round-nearest-even
  return (u16)(r >> 16);
}
__device__ __forceinline__ float bf2f(u16 u) {
  union { u32 u; float f; } v; v.u = ((u32)u) << 16;
  return v.f;
}
__device__ __forceinline__ void fma4(float4& acc, float a, const float4& w) {
  acc.x = fmaf(a, w.x, acc.x);
  acc.y = fmaf(a, w.y, acc.y);
  acc.z = fmaf(a, w.z, acc.z);
  acc.w = fmaf(a, w.w, acc.w);
}

// ---------- CSR build (shared) ----------
__global__ void k_count(const int* __restrict__ dsts, int* __restrict__ cnt, int E) {
  for (int e = blockIdx.x * blockDim.x + threadIdx.x; e < E;
       e += gridDim.x * blockDim.x)
    atomicAdd(&cnt[dsts[e]], 1);
}

__global__ __launch_bounds__(SCAN_T) void k_scan(int* __restrict__ cnt,
                                                 int* __restrict__ row_ptr) {
  __shared__ int part[SCAN_T];
  const int t = threadIdx.x;
  const int lo = t * SCAN_CH;
  const int hi = min(lo + SCAN_CH, NN);
  int s = 0;
  for (int i = lo; i < hi; ++i) s += cnt[i];
  part[t] = s;
  __syncthreads();
  for (int off = 1; off < SCAN_T; off <<= 1) {
    int v = (t >= off) ? part[t - off] : 0;
    __syncthreads();
    part[t] += v;
    __syncthreads();
  }
  int base = (t == 0) ? 0 : part[t - 1];
  for (int i = lo; i < hi; ++i) {
    const int c = cnt[i];
    row_ptr[i] = base;
    cnt[i] = base;
    base += c;
  }
  if (t == SCAN_T - 1) row_ptr[NN] = part[SCAN_T - 1];
}

__global__ void k_scatter(const int* __restrict__ srcs, const int* __restrict__ dsts,
                          int* __restrict__ cursor, int* __restrict__ csr, int E) {
  for (int e = blockIdx.x * blockDim.x + threadIdx.x; e < E;
       e += gridDim.x * blockDim.x) {
    const int pos = atomicAdd(&cursor[dsts[e]], 1);
    csr[pos] = srcs[e];
  }
}

// ---------- fast path: MFMA pipeline ----------
// P1: W1[128][256] -> W1tr bf16 [256 n][128 k]; W2[256][128] -> W2tr bf16 [128 n][256 k]
__global__ void k_wprep(const float* __restrict__ W1, const float* __restrict__ W2,
                        u16* __restrict__ w1tr, u16* __restrict__ w2tr) {
  const int t = blockIdx.x * blockDim.x + threadIdx.x;
  if (t < 32768) {
    const int n = t >> 7, k = t & 127;
    w1tr[t] = f2bf(W1[k * 256 + n]);
  } else if (t < 65536) {
    const int i = t - 32768;
    const int n = i >> 8, k = i & 255;
    w2tr[i] = f2bf(W2[k * 128 + n]);
  }
}

// P2: one wave per node -> h0bf bf16 [NN][128] in ws
__global__ __launch_bounds__(256) void k_aggregate_bf(const float* __restrict__ x,
    const float* __restrict__ epsp, const int* __restrict__ rowp,
    const int* __restrict__ csr, u16* __restrict__ h0bf) {
  const int lane = threadIdx.x & 63;
  const int wid = blockIdx.x * 4 + (threadIdx.x >> 6);
  const int nw = gridDim.x * 4;
  const float ep = 1.0f + epsp[0];
  for (int v = wid; v < NN; v += nw) {
    const float2 xv = ((const float2*)(x + (size_t)v * D))[lane];
    float2 acc;
    acc.x = ep * xv.x;
    acc.y = ep * xv.y;
    const int beg = rowp[v], end = rowp[v + 1];
    int j = beg;
    for (; j + 4 <= end; j += 4) {
      const int u0 = csr[j + 0], u1 = csr[j + 1];
      const int u2 = csr[j + 2], u3 = csr[j + 3];
      const float2 a0 = ((const float2*)(x + (size_t)u0 * D))[lane];
      const float2 a1 = ((const float2*)(x + (size_t)u1 * D))[lane];
      const float2 a2 = ((const float2*)(x + (size_t)u2 * D))[lane];
      const float2 a3 = ((const float2*)(x + (size_t)u3 * D))[lane];
      acc.x += a0.x + a1.x + a2.x + a3.x;
      acc.y += a0.y + a1.y + a2.y + a3.y;
    }
    for (; j < end; ++j) {
      const float2 a = ((const float2*)(x + (size_t)csr[j] * D))[lane];
      acc.x += a.x;
      acc.y += a.y;
    }
    const u32 pk = (u32)f2bf(acc.x) | ((u32)f2bf(acc.y) << 16);
    ((u32*)(h0bf + (size_t)v * D))[lane] = pk;
  }
}

// P3: h1[NN][256] bf16 (d_out) = h0bf @ W1tr^T + b1 via 32x32x16 bf16 MFMA.
// Wave tile: 32 rows x 128 cols (4 n-tiles). 6250 wave-tasks (3125 chunks x 2 cg).
__global__ __launch_bounds__(256) void k_gemm1_mfma(const u16* __restrict__ h0bf,
    const u16* __restrict__ w1tr, const float* __restrict__ b1, u16* __restrict__ h1) {
  const int lane = threadIdx.x & 63;
  const int l31 = lane & 31;
  const int khalf = (lane >> 5) * 8;      // 0 or 8
  const int gw = blockIdx.x * 4 + (threadIdx.x >> 6);
  const int nwv = gridDim.x * 4;
  for (int task = gw; task < (NN / 32) * 2; task += nwv) {
    const int chunk = task >> 1, cg = task & 1;
    const int arow = chunk * 32 + l31;
    f32x16 acc[4];
    #pragma unroll
    for (int i = 0; i < 4; ++i)
      #pragma unroll
      for (int j = 0; j < 16; ++j) acc[i][j] = 0.0f;
    const u16* ap = h0bf + (size_t)arow * 128 + khalf;
    const u16* bp = w1tr + ((size_t)(cg * 128 + l31)) * 128 + khalf;
    #pragma unroll
    for (int ks = 0; ks < 8; ++ks) {
      const short8v av = *(const short8v*)(ap + ks * 16);
      #pragma unroll
      for (int i = 0; i < 4; ++i) {
        const short8v bv = *(const short8v*)(bp + (size_t)i * 32 * 128 + ks * 16);
        acc[i] = __builtin_amdgcn_mfma_f32_32x32x16_bf16(av, bv, acc[i], 0, 0, 0);
      }
    }
    const int r0 = chunk * 32 + 4 * (lane >> 5);   // + (reg&3) + 8*(reg>>2)
    #pragma unroll
    for (int i = 0; i < 4; ++i) {
      const int col = cg * 128 + i * 32 + l31;
      const float bias = b1[col];
      #pragma unroll
      for (int g = 0; g < 4; ++g)
        #pragma unroll
        for (int j = 0; j < 4; ++j) {
          const int row = r0 + 8 * g + j;
          h1[(size_t)row * 256 + col] = f2bf(acc[i][g * 4 + j] + bias);
        }
    }
  }
}

// P4: column stats over h1 -> stats[0..255]=sum, [256..511]=sumsq
__global__ __launch_bounds__(256) void k_stats(const u16* h1, float* __restrict__ stats) {
  __shared__ float red[512];
  red[threadIdx.x] = 0.0f;
  red[threadIdx.x + 256] = 0.0f;
  __syncthreads();
  const int tid = blockIdx.x * blockDim.x + threadIdx.x;
  const int c0 = (tid * 8) & 255;
  float s[8], q[8];
  #pragma unroll
  for (int j = 0; j < 8; ++j) { s[j] = 0.0f; q[j] = 0.0f; }
  const int total = NN * D2 / 8;
  for (int i = tid; i < total; i += gridDim.x * blockDim.x) {
    const ushort8v v = ((const ushort8v*)h1)[i];
    #pragma unroll
    for (int j = 0; j < 8; ++j) {
      const float f = bf2f(v[j]);
      s[j] += f;
      q[j] += f * f;
    }
  }
  #pragma unroll
  for (int j = 0; j < 8; ++j) {
    atomicAdd(&red[c0 + j], s[j]);
    atomicAdd(&red[256 + c0 + j], q[j]);
  }
  __syncthreads();
  atomicAdd(&stats[threadIdx.x], red[threadIdx.x]);
  atomicAdd(&stats[threadIdx.x + 256], red[threadIdx.x + 256]);
}

__global__ void k_finalize(const float* __restrict__ gamma, const float* __restrict__ beta,
                           float* __restrict__ stats) {
  const int j = threadIdx.x;
  const float inv = 1.0f / (float)NN;
  const float mu = stats[j] * inv;
  const float var = fmaxf(stats[D2 + j] * inv - mu * mu, 0.0f);
  const float sc = gamma[j] * rsqrtf(var + 1e-5f);
  stats[2 * D2 + j] = sc;
  stats[3 * D2 + j] = beta[j] - mu * sc;
}

// P5: h1 = bf16(relu(s*h1+t)) in place
__global__ __launch_bounds__(256) void k_bnrelu(u16* h1, const float* __restrict__ stats) {
  const int tid = blockIdx.x * blockDim.x + threadIdx.x;
  const int c0 = (tid * 8) & 255;
  const float4 s0 = *(const float4*)(stats + 512 + c0);
  const float4 s1 = *(const float4*)(stats + 512 + c0 + 4);
  const float4 t0 = *(const float4*)(stats + 768 + c0);
  const float4 t1 = *(const float4*)(stats + 768 + c0 + 4);
  const float sv[8] = {s0.x, s0.y, s0.z, s0.w, s1.x, s1.y, s1.z, s1.w};
  const float tv[8] = {t0.x, t0.y, t0.z, t0.w, t1.x, t1.y, t1.z, t1.w};
  const int total = NN * D2 / 8;
  for (int i = tid; i < total; i += gridDim.x * blockDim.x) {
    ushort8v v = ((const ushort8v*)h1)[i];
    #pragma unroll
    for (int j = 0; j < 8; ++j)
      v[j] = f2bf(fmaxf(fmaf(bf2f(v[j]), sv[j], tv[j]), 0.0f));
    ((ushort8v*)h1)[i] = v;
  }
}

// P6: out[NN][128] f32 (in place over h1) = h1 @ W2tr^T + b2. 3125 wave-tasks.
// In-place safe: acc depends on ALL the wave's loads (MFMA is cross-lane), so
// every load of the 32-row chunk completes before any store.
__global__ __launch_bounds__(256) void k_gemm2_mfma(const u16* h1, float* outp,
    const u16* __restrict__ w2tr, const float* __restrict__ b2) {
  const int lane = threadIdx.x & 63;
  const int l31 = lane & 31;
  const int khalf = (lane >> 5) * 8;
  const int gw = blockIdx.x * 4 + (threadIdx.x >> 6);
  const int nwv = gridDim.x * 4;
  for (int chunk = gw; chunk < NN / 32; chunk += nwv) {
    const int arow = chunk * 32 + l31;
    f32x16 acc[4];
    #pragma unroll
    for (int i = 0; i < 4; ++i)
      #pragma unroll
      for (int j = 0; j < 16; ++j) acc[i][j] = 0.0f;
    const u16* ap = h1 + (size_t)arow * 256 + khalf;
    const u16* bp = w2tr + (size_t)l31 * 256 + khalf;
    #pragma unroll
    for (int ks = 0; ks < 16; ++ks) {
      const short8v av = *(const short8v*)(ap + ks * 16);
      #pragma unroll
      for (int i = 0; i < 4; ++i) {
        const short8v bv = *(const short8v*)(bp + (size_t)i * 32 * 256 + ks * 16);
        acc[i] = __builtin_amdgcn_mfma_f32_32x32x16_bf16(av, bv, acc[i], 0, 0, 0);
      }
    }
    const int r0 = chunk * 32 + 4 * (lane >> 5);
    #pragma unroll
    for (int i = 0; i < 4; ++i) {
      const int col = i * 32 + l31;
      const float bias = b2[col];
      #pragma unroll
      for (int g = 0; g < 4; ++g)
        #pragma unroll
        for (int j = 0; j < 4; ++j) {
          const int row = r0 + 8 * g + j;
          outp[(size_t)row * 128 + col] = acc[i][g * 4 + j] + bias;
        }
    }
  }
}

// ---------- fallback tier 2/3 kernels (proven R6/R8 paths) ----------
__global__ void k_init(const float* __restrict__ x, const float* __restrict__ epsp,
                       float* __restrict__ h0, float* __restrict__ stats) {
  if (blockIdx.x == 0 && threadIdx.x < 512) stats[threadIdx.x] = 0.0f;
  const float ep = 1.0f + epsp[0];
  const float4* x4 = (const float4*)x;
  float4* h4 = (float4*)h0;
  const int total = NN * D / 4;
  for (int i = blockIdx.x * blockDim.x + threadIdx.x; i < total;
       i += gridDim.x * blockDim.x) {
    float4 v = x4[i];
    v.x *= ep; v.y *= ep; v.z *= ep; v.w *= ep;
    h4[i] = v;
  }
}

__global__ void k_edges(const float* __restrict__ x, const int* __restrict__ srcs,
                        const int* __restrict__ dsts, float* __restrict__ h0, int E) {
  const int lane = threadIdx.x & 63;
  const int wave = blockIdx.x * (blockDim.x >> 6) + (threadIdx.x >> 6);
  const int e0 = wave * 8;
  const int e1 = min(e0 + 8, E);
  for (int e = e0; e < e1; ++e) {
    const int s = srcs[e];
    const int d = dsts[e];
    const float2 v = ((const float2*)(x + (size_t)s * D))[lane];
    float* p = h0 + (size_t)d * D + lane * 2;
    unsafeAtomicAdd(p, v.x);
    unsafeAtomicAdd(p + 1, v.y);
  }
}

__global__ __launch_bounds__(256) void k_aggregate_f32(const float* __restrict__ x,
    const float* __restrict__ epsp, const int* __restrict__ rowp,
    const int* __restrict__ csr, float* __restrict__ h0) {
  const int lane = threadIdx.x & 63;
  const int wid = blockIdx.x * 4 + (threadIdx.x >> 6);
  const int nw = gridDim.x * 4;
  const float ep = 1.0f + epsp[0];
  for (int v = wid; v < NN; v += nw) {
    const float2 xv = ((const float2*)(x + (size_t)v * D))[lane];
    float2 acc;
    acc.x = ep * xv.x;
    acc.y = ep * xv.y;
    const int beg = rowp[v], end = rowp[v + 1];
    for (int j = beg; j < end; ++j) {
      const float2 a = ((const float2*)(x + (size_t)csr[j] * D))[lane];
      acc.x += a.x;
      acc.y += a.y;
    }
    ((float2*)(h0 + (size_t)v * D))[lane] = acc;
  }
}

__global__ __launch_bounds__(1024) void k_gemm1_vec(const float* h0, u16* h1,
    const float* __restrict__ W1, const float* __restrict__ b1,
    float* __restrict__ stats) {
  __shared__ float4 sW[D * D2 / 4];
  const float4* Wv = (const float4*)W1;
  for (int i = threadIdx.x; i < D * D2 / 4; i += 1024) sW[i] = Wv[i];
  __syncthreads();
  const int lane = threadIdx.x & 63;
  const int wv = blockIdx.x * 16 + (threadIdx.x >> 6);
  const int nwv = gridDim.x * 16;
  const float4 bias = ((const float4*)b1)[lane];
  float ssum[4] = {0.f, 0.f, 0.f, 0.f};
  float sqs[4]  = {0.f, 0.f, 0.f, 0.f};
  for (int rb = wv * 8; rb < NN; rb += nwv * 8) {
    float4 acc[8];
    #pragma unroll
    for (int r = 0; r < 8; ++r) acc[r] = bias;
    for (int k4 = 0; k4 < D / 4; ++k4) {
      const float4 w0 = sW[(k4 * 4 + 0) * (D2 / 4) + lane];
      const float4 w1 = sW[(k4 * 4 + 1) * (D2 / 4) + lane];
      const float4 w2 = sW[(k4 * 4 + 2) * (D2 / 4) + lane];
      const float4 w3 = sW[(k4 * 4 + 3) * (D2 / 4) + lane];
      #pragma unroll
      for (int r = 0; r < 8; ++r) {
        const float4 a = ((const float4*)(h0 + (size_t)(rb + r) * D))[k4];
        fma4(acc[r], a.x, w0);
        fma4(acc[r], a.y, w1);
        fma4(acc[r], a.z, w2);
        fma4(acc[r], a.w, w3);
      }
    }
    #pragma unroll
    for (int r = 0; r < 8; ++r) {
      ushort4 o;
      o.x = f2bf(acc[r].x); o.y = f2bf(acc[r].y);
      o.z = f2bf(acc[r].z); o.w = f2bf(acc[r].w);
      ((ushort4*)h1)[(size_t)(rb + r) * (D2 / 4) + lane] = o;
      ssum[0] += acc[r].x; ssum[1] += acc[r].y;
      ssum[2] += acc[r].z; ssum[3] += acc[r].w;
      sqs[0] += acc[r].x * acc[r].x; sqs[1] += acc[r].y * acc[r].y;
      sqs[2] += acc[r].z * acc[r].z; sqs[3] += acc[r].w * acc[r].w;
    }
  }
  __syncthreads();
  float* red = (float*)sW;
  const int w = threadIdx.x >> 6;
  #pragma unroll
  for (int c = 0; c < 4; ++c) {
    red[w * 512 + lane * 4 + c] = ssum[c];
    red[w * 512 + 256 + lane * 4 + c] = sqs[c];
  }
  __syncthreads();
  if (threadIdx.x < 512) {
    float s = 0.f;
    #pragma unroll
    for (int ww = 0; ww < 16; ++ww) s += red[ww * 512 + threadIdx.x];
    unsafeAtomicAdd(&stats[threadIdx.x], s);
  }
}

__global__ __launch_bounds__(1024) void k_gemm2_vec(const u16* h1, float* outp,
    const float* __restrict__ W2, const float* __restrict__ b2,
    const float* __restrict__ stats) {
  __shared__ float4 sW[D2 * D / 4];
  __shared__ float sS[D2], sT[D2];
  const float4* Wv = (const float4*)W2;
  for (int i = threadIdx.x; i < D2 * D / 4; i += 1024) sW[i] = Wv[i];
  if (threadIdx.x < D2) {
    sS[threadIdx.x] = stats[2 * D2 + threadIdx.x];
    sT[threadIdx.x] = stats[3 * D2 + threadIdx.x];
  }
  __syncthreads();
  const float2* sWf2 = (const float2*)sW;
  const int lane = threadIdx.x & 63;
  const int wv = blockIdx.x * 16 + (threadIdx.x >> 6);
  const int nwv = gridDim.x * 16;
  const float2 bias = ((const float2*)b2)[lane];
  for (int rb = wv * 8; rb < NN; rb += nwv * 8) {
    float2 acc[8];
    #pragma unroll
    for (int r = 0; r < 8; ++r) acc[r] = bias;
    for (int k4 = 0; k4 < D2 / 4; ++k4) {
      const float4 sv = ((const float4*)sS)[k4];
      const float4 tv = ((const float4*)sT)[k4];
      const float2 w0 = sWf2[(k4 * 4 + 0) * 64 + lane];
      const float2 w1 = sWf2[(k4 * 4 + 1) * 64 + lane];
      const float2 w2 = sWf2[(k4 * 4 + 2) * 64 + lane];
      const float2 w3 = sWf2[(k4 * 4 + 3) * 64 + lane];
      #pragma unroll
      for (int r = 0; r < 8; ++r) {
        const ushort4 a = ((const ushort4*)h1)[(size_t)(rb + r) * 64 + k4];
        const float ha = fmaxf(fmaf(bf2f(a.x), sv.x, tv.x), 0.f);
        const float hb = fmaxf(fmaf(bf2f(a.y), sv.y, tv.y), 0.f);
        const float hc = fmaxf(fmaf(bf2f(a.z), sv.z, tv.z), 0.f);
        const float hd = fmaxf(fmaf(bf2f(a.w), sv.w, tv.w), 0.f);
        acc[r].x = fmaf(ha, w0.x, acc[r].x); acc[r].y = fmaf(ha, w0.y, acc[r].y);
        acc[r].x = fmaf(hb, w1.x, acc[r].x); acc[r].y = fmaf(hb, w1.y, acc[r].y);
        acc[r].x = fmaf(hc, w2.x, acc[r].x); acc[r].y = fmaf(hc, w2.y, acc[r].y);
        acc[r].x = fmaf(hd, w3.x, acc[r].x); acc[r].y = fmaf(hd, w3.y, acc[r].y);
      }
    }
    #pragma unroll
    for (int r = 0; r < 8; ++r)
      ((float2*)outp)[(size_t)(rb + r) * 64 + lane] = acc[r];
  }
}

extern "C" void kernel_launch(void* const* d_in, const int* in_sizes, int n_in,
                              void* d_out, int out_size, void* d_ws, size_t ws_size,
                              hipStream_t stream) {
  const float* x     = (const float*)d_in[0];
  const int* ei      = (const int*)d_in[1];     // int32 (harness converts int64)
  const float* W1    = (const float*)d_in[2];
  const float* b1    = (const float*)d_in[3];
  const float* gamma = (const float*)d_in[4];
  const float* beta  = (const float*)d_in[5];
  const float* W2    = (const float*)d_in[6];
  const float* b2    = (const float*)d_in[7];
  const float* eps   = (const float*)d_in[8];
  const int E = in_sizes[1] / 2;

  float* out   = (float*)d_out;
  float* stats = (float*)d_ws;                  // 4 KB: sum|sumsq|s|t
  int* cnt  = (int*)((char*)d_ws + 4096);       // NN ints (doubles as cursor)
  int* rowp = cnt + NN;                         // NN+1 ints
  int* csr  = rowp + NN + 1;                    // E ints
  size_t off = 4096 + sizeof(int) * ((size_t)NN + (NN + 1) + E);
  off = (off + 511) & ~(size_t)511;
  u16* h0bf = (u16*)((char*)d_ws + off);        // NN*128 bf16 = 25.6 MB
  u16* w1tr = h0bf + (size_t)NN * D;            // 256*128 bf16
  u16* w2tr = w1tr + D2 * D;                    // 128*256 bf16
  const size_t need_fast = off + 2u * ((size_t)NN * D + D2 * D + D * D2);
  const size_t need_csr  = 4096 + sizeof(int) * ((size_t)NN + (NN + 1) + E);

  if (ws_size >= need_fast) {
    hipMemsetAsync(d_ws, 0, 4096 + (size_t)NN * 4, stream);  // stats + cnt
    k_count<<<2048, 256, 0, stream>>>(ei + E, cnt, E);
    k_scan<<<1, SCAN_T, 0, stream>>>(cnt, rowp);
    k_scatter<<<2048, 256, 0, stream>>>(ei, ei + E, cnt, csr, E);
    k_wprep<<<256, 256, 0, stream>>>(W1, W2, w1tr, w2tr);
    k_aggregate_bf<<<1600, 256, 0, stream>>>(x, eps, rowp, csr, h0bf);
    k_gemm1_mfma<<<1563, 256, 0, stream>>>(h0bf, w1tr, b1, (u16*)out);
    k_stats<<<256, 256, 0, stream>>>((const u16*)out, stats);
    k_finalize<<<1, 256, 0, stream>>>(gamma, beta, stats);
    k_bnrelu<<<2048, 256, 0, stream>>>((u16*)out, stats);
    k_gemm2_mfma<<<782, 256, 0, stream>>>((const u16*)out, out, w2tr, b2);
  } else if (ws_size >= need_csr) {
    hipMemsetAsync(d_ws, 0, 4096 + (size_t)NN * 4, stream);
    k_count<<<2048, 256, 0, stream>>>(ei + E, cnt, E);
    k_scan<<<1, SCAN_T, 0, stream>>>(cnt, rowp);
    k_scatter<<<2048, 256, 0, stream>>>(ei, ei + E, cnt, csr, E);
    k_aggregate_f32<<<1600, 256, 0, stream>>>(x, eps, rowp, csr, out);
    k_gemm1_vec<<<256, 1024, 0, stream>>>(out, (u16*)out, W1, b1, stats);
    k_finalize<<<1, 256, 0, stream>>>(gamma, beta, stats);
    k_gemm2_vec<<<256, 1024, 0, stream>>>((const u16*)out, out, W2, b2, stats);
  } else {
    k_init<<<2048, 256, 0, stream>>>(x, eps, out, stats);
    k_edges<<<(E + 31) / 32, 256, 0, stream>>>(x, ei, ei + E, out, E);
    k_gemm1_vec<<<256, 1024, 0, stream>>>(out, (u16*)out, W1, b1, stats);
    k_finalize<<<1, 256, 0, stream>>>(gamma, beta, stats);
    k_gemm2_vec<<<256, 1024, 0, stream>>>((const u16*)out, out, W2, b2, stats);
  }
}

// Round 11
// 1009.365 us; speedup vs baseline: 3.1018x; 1.0814x over previous
//
#include <hip/hip_runtime.h>

#define NN 100000
#define D 128
#define D2 256
#define SCAN_T 1024
#define SCAN_CH ((NN + SCAN_T - 1) / SCAN_T)   // 98

typedef unsigned short u16;
typedef unsigned int u32;
typedef __attribute__((ext_vector_type(8))) short short8v;
typedef __attribute__((ext_vector_type(8))) unsigned short ushort8v;
typedef __attribute__((ext_vector_type(16))) float f32x16;

__device__ __forceinline__ u16 f2bf(float f) {
  union { float f; u32 u; } v; v.f = f;
  u32 r = v.u + 0x7fffu + ((v.u >> 16) & 1u);   // round-nearest-even
  return (u16)(r >> 16);
}
__device__ __forceinline__ float bf2f(u16 u) {
  union { u32 u; float f; } v; v.u = ((u32)u) << 16;
  return v.f;
}
__device__ __forceinline__ void fma4(float4& acc, float a, const float4& w) {
  acc.x = fmaf(a, w.x, acc.x);
  acc.y = fmaf(a, w.y, acc.y);
  acc.z = fmaf(a, w.z, acc.z);
  acc.w = fmaf(a, w.w, acc.w);
}

// ---------- CSR build ----------
// C1: degree count, 4x unrolled for atomic ILP (latency-bound, VALUBusy 0.3%)
__global__ void k_count(const int* __restrict__ dsts, int* __restrict__ cnt, int E) {
  const int stride = gridDim.x * blockDim.x;
  int i = blockIdx.x * blockDim.x + threadIdx.x;
  for (; i + 3 * stride < E; i += 4 * stride) {
    const int d0 = dsts[i];
    const int d1 = dsts[i + stride];
    const int d2 = dsts[i + 2 * stride];
    const int d3 = dsts[i + 3 * stride];
    atomicAdd(&cnt[d0], 1);
    atomicAdd(&cnt[d1], 1);
    atomicAdd(&cnt[d2], 1);
    atomicAdd(&cnt[d3], 1);
  }
  for (; i < E; i += stride) atomicAdd(&cnt[dsts[i]], 1);
}

__global__ __launch_bounds__(SCAN_T) void k_scan(int* __restrict__ cnt,
                                                 int* __restrict__ row_ptr) {
  __shared__ int part[SCAN_T];
  const int t = threadIdx.x;
  const int lo = t * SCAN_CH;
  const int hi = min(lo + SCAN_CH, NN);
  int s = 0;
  for (int i = lo; i < hi; ++i) s += cnt[i];
  part[t] = s;
  __syncthreads();
  for (int off = 1; off < SCAN_T; off <<= 1) {
    int v = (t >= off) ? part[t - off] : 0;
    __syncthreads();
    part[t] += v;
    __syncthreads();
  }
  int base = (t == 0) ? 0 : part[t - 1];
  for (int i = lo; i < hi; ++i) {
    const int c = cnt[i];
    row_ptr[i] = base;
    cnt[i] = base;
    base += c;
  }
  if (t == SCAN_T - 1) row_ptr[NN] = part[SCAN_T - 1];
}

// C3: scatter, 4x unrolled (batch loads -> batch atomics -> batch stores)
__global__ void k_scatter(const int* __restrict__ srcs, const int* __restrict__ dsts,
                          int* __restrict__ cursor, int* __restrict__ csr, int E) {
  const int stride = gridDim.x * blockDim.x;
  int i = blockIdx.x * blockDim.x + threadIdx.x;
  for (; i + 3 * stride < E; i += 4 * stride) {
    const int d0 = dsts[i];
    const int d1 = dsts[i + stride];
    const int d2 = dsts[i + 2 * stride];
    const int d3 = dsts[i + 3 * stride];
    const int s0 = srcs[i];
    const int s1 = srcs[i + stride];
    const int s2 = srcs[i + 2 * stride];
    const int s3 = srcs[i + 3 * stride];
    const int p0 = atomicAdd(&cursor[d0], 1);
    const int p1 = atomicAdd(&cursor[d1], 1);
    const int p2 = atomicAdd(&cursor[d2], 1);
    const int p3 = atomicAdd(&cursor[d3], 1);
    csr[p0] = s0;
    csr[p1] = s1;
    csr[p2] = s2;
    csr[p3] = s3;
  }
  for (; i < E; i += stride) {
    const int pos = atomicAdd(&cursor[dsts[i]], 1);
    csr[pos] = srcs[i];
  }
}

// ---------- fast path prep ----------
// P1: weights -> bf16 [n][k]
__global__ void k_wprep(const float* __restrict__ W1, const float* __restrict__ W2,
                        u16* __restrict__ w1tr, u16* __restrict__ w2tr) {
  const int t = blockIdx.x * blockDim.x + threadIdx.x;
  if (t < 32768) {
    const int n = t >> 7, k = t & 127;
    w1tr[t] = f2bf(W1[k * 256 + n]);
  } else if (t < 65536) {
    const int i = t - 32768;
    const int n = i >> 8, k = i & 255;
    w2tr[i] = f2bf(W2[k * 128 + n]);
  }
}

// P1b: x -> bf16 (halves gather traffic in aggregation)
__global__ void k_xbf(const float* __restrict__ x, u16* __restrict__ xbf) {
  const int total = NN * D / 4;
  for (int i = blockIdx.x * blockDim.x + threadIdx.x; i < total;
       i += gridDim.x * blockDim.x) {
    const float4 v = ((const float4*)x)[i];
    ushort4 o;
    o.x = f2bf(v.x); o.y = f2bf(v.y); o.z = f2bf(v.z); o.w = f2bf(v.w);
    ((ushort4*)xbf)[i] = o;
  }
}

// P2 (fast2): one wave per node, gathers bf16 x rows (256 B/row), 8-deep ILP.
// Self term from f32 x for precision.
__global__ __launch_bounds__(256) void k_aggregate_bf2(const float* __restrict__ x,
    const u16* __restrict__ xbf, const float* __restrict__ epsp,
    const int* __restrict__ rowp, const int* __restrict__ csr,
    u16* __restrict__ h0bf) {
  const int lane = threadIdx.x & 63;
  const int wid = blockIdx.x * 4 + (threadIdx.x >> 6);
  const int nw = gridDim.x * 4;
  const float ep = 1.0f + epsp[0];
  for (int v = wid; v < NN; v += nw) {
    const float2 xv = ((const float2*)(x + (size_t)v * D))[lane];
    float ax = ep * xv.x;
    float ay = ep * xv.y;
    const int beg = rowp[v], end = rowp[v + 1];
    int j = beg;
    for (; j + 8 <= end; j += 8) {
      u32 w[8];
      #pragma unroll
      for (int q = 0; q < 8; ++q) {
        const int u = csr[j + q];
        w[q] = ((const u32*)(xbf + (size_t)u * D))[lane];
      }
      #pragma unroll
      for (int q = 0; q < 8; ++q) {
        ax += bf2f((u16)(w[q] & 0xffffu));
        ay += bf2f((u16)(w[q] >> 16));
      }
    }
    for (; j < end; ++j) {
      const u32 w0 = ((const u32*)(xbf + (size_t)csr[j] * D))[lane];
      ax += bf2f((u16)(w0 & 0xffffu));
      ay += bf2f((u16)(w0 >> 16));
    }
    const u32 pk = (u32)f2bf(ax) | ((u32)f2bf(ay) << 16);
    ((u32*)(h0bf + (size_t)v * D))[lane] = pk;
  }
}

// P2 (fast1 fallback): f32 gather variant (R10-proven)
__global__ __launch_bounds__(256) void k_aggregate_bf(const float* __restrict__ x,
    const float* __restrict__ epsp, const int* __restrict__ rowp,
    const int* __restrict__ csr, u16* __restrict__ h0bf) {
  const int lane = threadIdx.x & 63;
  const int wid = blockIdx.x * 4 + (threadIdx.x >> 6);
  const int nw = gridDim.x * 4;
  const float ep = 1.0f + epsp[0];
  for (int v = wid; v < NN; v += nw) {
    const float2 xv = ((const float2*)(x + (size_t)v * D))[lane];
    float2 acc;
    acc.x = ep * xv.x;
    acc.y = ep * xv.y;
    const int beg = rowp[v], end = rowp[v + 1];
    int j = beg;
    for (; j + 4 <= end; j += 4) {
      const int u0 = csr[j + 0], u1 = csr[j + 1];
      const int u2 = csr[j + 2], u3 = csr[j + 3];
      const float2 a0 = ((const float2*)(x + (size_t)u0 * D))[lane];
      const float2 a1 = ((const float2*)(x + (size_t)u1 * D))[lane];
      const float2 a2 = ((const float2*)(x + (size_t)u2 * D))[lane];
      const float2 a3 = ((const float2*)(x + (size_t)u3 * D))[lane];
      acc.x += a0.x + a1.x + a2.x + a3.x;
      acc.y += a0.y + a1.y + a2.y + a3.y;
    }
    for (; j < end; ++j) {
      const float2 a = ((const float2*)(x + (size_t)csr[j] * D))[lane];
      acc.x += a.x;
      acc.y += a.y;
    }
    const u32 pk = (u32)f2bf(acc.x) | ((u32)f2bf(acc.y) << 16);
    ((u32*)(h0bf + (size_t)v * D))[lane] = pk;
  }
}

// P3: h1 = h0bf @ W1tr^T + b1 (MFMA) with FUSED BN stats (LDS-reduced).
// stats[0..255]=sum, [256..511]=sumsq (pre-zeroed by memset).
__global__ __launch_bounds__(256) void k_gemm1_mfma(const u16* __restrict__ h0bf,
    const u16* __restrict__ w1tr, const float* __restrict__ b1, u16* __restrict__ h1,
    float* __restrict__ stats) {
  __shared__ float ls[512];
  if (threadIdx.x < 256) { ls[threadIdx.x] = 0.0f; ls[threadIdx.x + 256] = 0.0f; }
  __syncthreads();
  const int lane = threadIdx.x & 63;
  const int l31 = lane & 31;
  const int khalf = (lane >> 5) * 8;      // 0 or 8
  const int gw = blockIdx.x * 4 + (threadIdx.x >> 6);
  const int nwv = gridDim.x * 4;
  for (int task = gw; task < (NN / 32) * 2; task += nwv) {
    const int chunk = task >> 1, cg = task & 1;
    const int arow = chunk * 32 + l31;
    f32x16 acc[4];
    #pragma unroll
    for (int i = 0; i < 4; ++i)
      #pragma unroll
      for (int j = 0; j < 16; ++j) acc[i][j] = 0.0f;
    const u16* ap = h0bf + (size_t)arow * 128 + khalf;
    const u16* bp = w1tr + ((size_t)(cg * 128 + l31)) * 128 + khalf;
    #pragma unroll
    for (int ks = 0; ks < 8; ++ks) {
      const short8v av = *(const short8v*)(ap + ks * 16);
      #pragma unroll
      for (int i = 0; i < 4; ++i) {
        const short8v bv = *(const short8v*)(bp + (size_t)i * 32 * 128 + ks * 16);
        acc[i] = __builtin_amdgcn_mfma_f32_32x32x16_bf16(av, bv, acc[i], 0, 0, 0);
      }
    }
    const int r0 = chunk * 32 + 4 * (lane >> 5);   // + (reg&3) + 8*(reg>>2)
    #pragma unroll
    for (int i = 0; i < 4; ++i) {
      const int col = cg * 128 + i * 32 + l31;
      const float bias = b1[col];
      float psum = 0.0f, psq = 0.0f;
      #pragma unroll
      for (int g = 0; g < 4; ++g)
        #pragma unroll
        for (int j = 0; j < 4; ++j) {
          const int row = r0 + 8 * g + j;
          const float h = acc[i][g * 4 + j] + bias;
          h1[(size_t)row * 256 + col] = f2bf(h);
          psum += h;
          psq += h * h;
        }
      unsafeAtomicAdd(&ls[col], psum);
      unsafeAtomicAdd(&ls[col + 256], psq);
    }
  }
  __syncthreads();
  if (threadIdx.x < 256) {
    unsafeAtomicAdd(&stats[threadIdx.x], ls[threadIdx.x]);
    unsafeAtomicAdd(&stats[threadIdx.x + 256], ls[threadIdx.x + 256]);
  }
}

__global__ void k_finalize(const float* __restrict__ gamma, const float* __restrict__ beta,
                           float* __restrict__ stats) {
  const int j = threadIdx.x;
  const float inv = 1.0f / (float)NN;
  const float mu = stats[j] * inv;
  const float var = fmaxf(stats[D2 + j] * inv - mu * mu, 0.0f);
  const float sc = gamma[j] * rsqrtf(var + 1e-5f);
  stats[2 * D2 + j] = sc;
  stats[3 * D2 + j] = beta[j] - mu * sc;
}

// P5: h1 = bf16(relu(s*h1+t)) in place
__global__ __launch_bounds__(256) void k_bnrelu(u16* h1, const float* __restrict__ stats) {
  const int tid = blockIdx.x * blockDim.x + threadIdx.x;
  const int c0 = (tid * 8) & 255;
  const float4 s0 = *(const float4*)(stats + 512 + c0);
  const float4 s1 = *(const float4*)(stats + 512 + c0 + 4);
  const float4 t0 = *(const float4*)(stats + 768 + c0);
  const float4 t1 = *(const float4*)(stats + 768 + c0 + 4);
  const float sv[8] = {s0.x, s0.y, s0.z, s0.w, s1.x, s1.y, s1.z, s1.w};
  const float tv[8] = {t0.x, t0.y, t0.z, t0.w, t1.x, t1.y, t1.z, t1.w};
  const int total = NN * D2 / 8;
  for (int i = tid; i < total; i += gridDim.x * blockDim.x) {
    ushort8v v = ((const ushort8v*)h1)[i];
    #pragma unroll
    for (int j = 0; j < 8; ++j)
      v[j] = f2bf(fmaxf(fmaf(bf2f(v[j]), sv[j], tv[j]), 0.0f));
    ((ushort8v*)h1)[i] = v;
  }
}

// P6: out = h1 @ W2tr^T + b2 (MFMA), in place over h1.
__global__ __launch_bounds__(256) void k_gemm2_mfma(const u16* h1, float* outp,
    const u16* __restrict__ w2tr, const float* __restrict__ b2) {
  const int lane = threadIdx.x & 63;
  const int l31 = lane & 31;
  const int khalf = (lane >> 5) * 8;
  const int gw = blockIdx.x * 4 + (threadIdx.x >> 6);
  const int nwv = gridDim.x * 4;
  for (int chunk = gw; chunk < NN / 32; chunk += nwv) {
    const int arow = chunk * 32 + l31;
    f32x16 acc[4];
    #pragma unroll
    for (int i = 0; i < 4; ++i)
      #pragma unroll
      for (int j = 0; j < 16; ++j) acc[i][j] = 0.0f;
    const u16* ap = h1 + (size_t)arow * 256 + khalf;
    const u16* bp = w2tr + (size_t)l31 * 256 + khalf;
    #pragma unroll
    for (int ks = 0; ks < 16; ++ks) {
      const short8v av = *(const short8v*)(ap + ks * 16);
      #pragma unroll
      for (int i = 0; i < 4; ++i) {
        const short8v bv = *(const short8v*)(bp + (size_t)i * 32 * 256 + ks * 16);
        acc[i] = __builtin_amdgcn_mfma_f32_32x32x16_bf16(av, bv, acc[i], 0, 0, 0);
      }
    }
    const int r0 = chunk * 32 + 4 * (lane >> 5);
    #pragma unroll
    for (int i = 0; i < 4; ++i) {
      const int col = i * 32 + l31;
      const float bias = b2[col];
      #pragma unroll
      for (int g = 0; g < 4; ++g)
        #pragma unroll
        for (int j = 0; j < 4; ++j) {
          const int row = r0 + 8 * g + j;
          outp[(size_t)row * 128 + col] = acc[i][g * 4 + j] + bias;
        }
    }
  }
}

// ---------- fallback tier 3/4 kernels (proven R6/R8 paths) ----------
__global__ void k_init(const float* __restrict__ x, const float* __restrict__ epsp,
                       float* __restrict__ h0, float* __restrict__ stats) {
  if (blockIdx.x == 0 && threadIdx.x < 512) stats[threadIdx.x] = 0.0f;
  const float ep = 1.0f + epsp[0];
  const float4* x4 = (const float4*)x;
  float4* h4 = (float4*)h0;
  const int total = NN * D / 4;
  for (int i = blockIdx.x * blockDim.x + threadIdx.x; i < total;
       i += gridDim.x * blockDim.x) {
    float4 v = x4[i];
    v.x *= ep; v.y *= ep; v.z *= ep; v.w *= ep;
    h4[i] = v;
  }
}

__global__ void k_edges(const float* __restrict__ x, const int* __restrict__ srcs,
                        const int* __restrict__ dsts, float* __restrict__ h0, int E) {
  const int lane = threadIdx.x & 63;
  const int wave = blockIdx.x * (blockDim.x >> 6) + (threadIdx.x >> 6);
  const int e0 = wave * 8;
  const int e1 = min(e0 + 8, E);
  for (int e = e0; e < e1; ++e) {
    const int s = srcs[e];
    const int d = dsts[e];
    const float2 v = ((const float2*)(x + (size_t)s * D))[lane];
    float* p = h0 + (size_t)d * D + lane * 2;
    unsafeAtomicAdd(p, v.x);
    unsafeAtomicAdd(p + 1, v.y);
  }
}

__global__ __launch_bounds__(256) void k_aggregate_f32(const float* __restrict__ x,
    const float* __restrict__ epsp, const int* __restrict__ rowp,
    const int* __restrict__ csr, float* __restrict__ h0) {
  const int lane = threadIdx.x & 63;
  const int wid = blockIdx.x * 4 + (threadIdx.x >> 6);
  const int nw = gridDim.x * 4;
  const float ep = 1.0f + epsp[0];
  for (int v = wid; v < NN; v += nw) {
    const float2 xv = ((const float2*)(x + (size_t)v * D))[lane];
    float2 acc;
    acc.x = ep * xv.x;
    acc.y = ep * xv.y;
    const int beg = rowp[v], end = rowp[v + 1];
    for (int j = beg; j < end; ++j) {
      const float2 a = ((const float2*)(x + (size_t)csr[j] * D))[lane];
      acc.x += a.x;
      acc.y += a.y;
    }
    ((float2*)(h0 + (size_t)v * D))[lane] = acc;
  }
}

__global__ __launch_bounds__(1024) void k_gemm1_vec(const float* h0, u16* h1,
    const float* __restrict__ W1, const float* __restrict__ b1,
    float* __restrict__ stats) {
  __shared__ float4 sW[D * D2 / 4];
  const float4* Wv = (const float4*)W1;
  for (int i = threadIdx.x; i < D * D2 / 4; i += 1024) sW[i] = Wv[i];
  __syncthreads();
  const int lane = threadIdx.x & 63;
  const int wv = blockIdx.x * 16 + (threadIdx.x >> 6);
  const int nwv = gridDim.x * 16;
  const float4 bias = ((const float4*)b1)[lane];
  float ssum[4] = {0.f, 0.f, 0.f, 0.f};
  float sqs[4]  = {0.f, 0.f, 0.f, 0.f};
  for (int rb = wv * 8; rb < NN; rb += nwv * 8) {
    float4 acc[8];
    #pragma unroll
    for (int r = 0; r < 8; ++r) acc[r] = bias;
    for (int k4 = 0; k4 < D / 4; ++k4) {
      const float4 w0 = sW[(k4 * 4 + 0) * (D2 / 4) + lane];
      const float4 w1 = sW[(k4 * 4 + 1) * (D2 / 4) + lane];
      const float4 w2 = sW[(k4 * 4 + 2) * (D2 / 4) + lane];
      const float4 w3 = sW[(k4 * 4 + 3) * (D2 / 4) + lane];
      #pragma unroll
      for (int r = 0; r < 8; ++r) {
        const float4 a = ((const float4*)(h0 + (size_t)(rb + r) * D))[k4];
        fma4(acc[r], a.x, w0);
        fma4(acc[r], a.y, w1);
        fma4(acc[r], a.z, w2);
        fma4(acc[r], a.w, w3);
      }
    }
    #pragma unroll
    for (int r = 0; r < 8; ++r) {
      ushort4 o;
      o.x = f2bf(acc[r].x); o.y = f2bf(acc[r].y);
      o.z = f2bf(acc[r].z); o.w = f2bf(acc[r].w);
      ((ushort4*)h1)[(size_t)(rb + r) * (D2 / 4) + lane] = o;
      ssum[0] += acc[r].x; ssum[1] += acc[r].y;
      ssum[2] += acc[r].z; ssum[3] += acc[r].w;
      sqs[0] += acc[r].x * acc[r].x; sqs[1] += acc[r].y * acc[r].y;
      sqs[2] += acc[r].z * acc[r].z; sqs[3] += acc[r].w * acc[r].w;
    }
  }
  __syncthreads();
  float* red = (float*)sW;
  const int w = threadIdx.x >> 6;
  #pragma unroll
  for (int c = 0; c < 4; ++c) {
    red[w * 512 + lane * 4 + c] = ssum[c];
    red[w * 512 + 256 + lane * 4 + c] = sqs[c];
  }
  __syncthreads();
  if (threadIdx.x < 512) {
    float s = 0.f;
    #pragma unroll
    for (int ww = 0; ww < 16; ++ww) s += red[ww * 512 + threadIdx.x];
    unsafeAtomicAdd(&stats[threadIdx.x], s);
  }
}

__global__ __launch_bounds__(1024) void k_gemm2_vec(const u16* h1, float* outp,
    const float* __restrict__ W2, const float* __restrict__ b2,
    const float* __restrict__ stats) {
  __shared__ float4 sW[D2 * D / 4];
  __shared__ float sS[D2], sT[D2];
  const float4* Wv = (const float4*)W2;
  for (int i = threadIdx.x; i < D2 * D / 4; i += 1024) sW[i] = Wv[i];
  if (threadIdx.x < D2) {
    sS[threadIdx.x] = stats[2 * D2 + threadIdx.x];
    sT[threadIdx.x] = stats[3 * D2 + threadIdx.x];
  }
  __syncthreads();
  const float2* sWf2 = (const float2*)sW;
  const int lane = threadIdx.x & 63;
  const int wv = blockIdx.x * 16 + (threadIdx.x >> 6);
  const int nwv = gridDim.x * 16;
  const float2 bias = ((const float2*)b2)[lane];
  for (int rb = wv * 8; rb < NN; rb += nwv * 8) {
    float2 acc[8];
    #pragma unroll
    for (int r = 0; r < 8; ++r) acc[r] = bias;
    for (int k4 = 0; k4 < D2 / 4; ++k4) {
      const float4 sv = ((const float4*)sS)[k4];
      const float4 tv = ((const float4*)sT)[k4];
      const float2 w0 = sWf2[(k4 * 4 + 0) * 64 + lane];
      const float2 w1 = sWf2[(k4 * 4 + 1) * 64 + lane];
      const float2 w2 = sWf2[(k4 * 4 + 2) * 64 + lane];
      const float2 w3 = sWf2[(k4 * 4 + 3) * 64 + lane];
      #pragma unroll
      for (int r = 0; r < 8; ++r) {
        const ushort4 a = ((const ushort4*)h1)[(size_t)(rb + r) * 64 + k4];
        const float ha = fmaxf(fmaf(bf2f(a.x), sv.x, tv.x), 0.f);
        const float hb = fmaxf(fmaf(bf2f(a.y), sv.y, tv.y), 0.f);
        const float hc = fmaxf(fmaf(bf2f(a.z), sv.z, tv.z), 0.f);
        const float hd = fmaxf(fmaf(bf2f(a.w), sv.w, tv.w), 0.f);
        acc[r].x = fmaf(ha, w0.x, acc[r].x); acc[r].y = fmaf(ha, w0.y, acc[r].y);
        acc[r].x = fmaf(hb, w1.x, acc[r].x); acc[r].y = fmaf(hb, w1.y, acc[r].y);
        acc[r].x = fmaf(hc, w2.x, acc[r].x); acc[r].y = fmaf(hc, w2.y, acc[r].y);
        acc[r].x = fmaf(hd, w3.x, acc[r].x); acc[r].y = fmaf(hd, w3.y, acc[r].y);
      }
    }
    #pragma unroll
    for (int r = 0; r < 8; ++r)
      ((float2*)outp)[(size_t)(rb + r) * 64 + lane] = acc[r];
  }
}

extern "C" void kernel_launch(void* const* d_in, const int* in_sizes, int n_in,
                              void* d_out, int out_size, void* d_ws, size_t ws_size,
                              hipStream_t stream) {
  const float* x     = (const float*)d_in[0];
  const int* ei      = (const int*)d_in[1];     // int32 (harness converts int64)
  const float* W1    = (const float*)d_in[2];
  const float* b1    = (const float*)d_in[3];
  const float* gamma = (const float*)d_in[4];
  const float* beta  = (const float*)d_in[5];
  const float* W2    = (const float*)d_in[6];
  const float* b2    = (const float*)d_in[7];
  const float* eps   = (const float*)d_in[8];
  const int E = in_sizes[1] / 2;

  float* out   = (float*)d_out;
  float* stats = (float*)d_ws;                  // 4 KB: sum|sumsq|s|t
  int* cnt  = (int*)((char*)d_ws + 4096);       // NN ints (doubles as cursor)
  int* rowp = cnt + NN;                         // NN+1 ints
  int* csr  = rowp + NN + 1;                    // E ints
  size_t off = 4096 + sizeof(int) * ((size_t)NN + (NN + 1) + E);
  off = (off + 511) & ~(size_t)511;
  u16* h0bf = (u16*)((char*)d_ws + off);        // NN*128 bf16 = 25.6 MB
  u16* w1tr = h0bf + (size_t)NN * D;            // 256*128 bf16
  u16* w2tr = w1tr + D2 * D;                    // 128*256 bf16
  u16* xbf  = w2tr + D * D2;                    // NN*128 bf16 = 25.6 MB
  const size_t need_f1 = off + 2u * ((size_t)NN * D + D2 * D + D * D2);
  const size_t need_f2 = need_f1 + 2u * (size_t)NN * D;
  const size_t need_csr = 4096 + sizeof(int) * ((size_t)NN + (NN + 1) + E);

  if (ws_size >= need_f1) {
    hipMemsetAsync(d_ws, 0, 4096 + (size_t)NN * 4, stream);  // stats + cnt
    k_count<<<2048, 256, 0, stream>>>(ei + E, cnt, E);
    k_scan<<<1, SCAN_T, 0, stream>>>(cnt, rowp);
    k_scatter<<<2048, 256, 0, stream>>>(ei, ei + E, cnt, csr, E);
    k_wprep<<<256, 256, 0, stream>>>(W1, W2, w1tr, w2tr);
    if (ws_size >= need_f2) {
      k_xbf<<<2048, 256, 0, stream>>>(x, xbf);
      k_aggregate_bf2<<<1600, 256, 0, stream>>>(x, xbf, eps, rowp, csr, h0bf);
    } else {
      k_aggregate_bf<<<1600, 256, 0, stream>>>(x, eps, rowp, csr, h0bf);
    }
    k_gemm1_mfma<<<1563, 256, 0, stream>>>(h0bf, w1tr, b1, (u16*)out, stats);
    k_finalize<<<1, 256, 0, stream>>>(gamma, beta, stats);
    k_bnrelu<<<2048, 256, 0, stream>>>((u16*)out, stats);
    k_gemm2_mfma<<<782, 256, 0, stream>>>((const u16*)out, out, w2tr, b2);
  } else if (ws_size >= need_csr) {
    hipMemsetAsync(d_ws, 0, 4096 + (size_t)NN * 4, stream);
    k_count<<<2048, 256, 0, stream>>>(ei + E, cnt, E);
    k_scan<<<1, SCAN_T, 0, stream>>>(cnt, rowp);
    k_scatter<<<2048, 256, 0, stream>>>(ei, ei + E, cnt, csr, E);
    k_aggregate_f32<<<1600, 256, 0, stream>>>(x, eps, rowp, csr, out);
    k_gemm1_vec<<<256, 1024, 0, stream>>>(out, (u16*)out, W1, b1, stats);
    k_finalize<<<1, 256, 0, stream>>>(gamma, beta, stats);
    k_gemm2_vec<<<256, 1024, 0, stream>>>((const u16*)out, out, W2, b2, stats);
  } else {
    k_init<<<2048, 256, 0, stream>>>(x, eps, out, stats);
    k_edges<<<(E + 31) / 32, 256, 0, stream>>>(x, ei, ei + E, out, E);
    k_gemm1_vec<<<256, 1024, 0, stream>>>(out, (u16*)out, W1, b1, stats);
    k_finalize<<<1, 256, 0, stream>>>(gamma, beta, stats);
    k_gemm2_vec<<<256, 1024, 0, stream>>>((const u16*)out, out, W2, b2, stats);
  }
}